// Round 2
// baseline (738.817 us; speedup 1.0000x reference)
//
#include <hip/hip_runtime.h>
#include <cstdint>
#include <cstddef>

// Multi-head causal attention forward. B=2, H=16, S=2048, EMBED=1024, D_K=64.
// d_out = out [2,2048,1024] fp32 ++ attn [2,16,2048,2048] fp32  (553.6 MB).
//
// Two kernels:
//  K1: row sums of exp(q.k/8) -> inv rowsum in d_ws (2*16*2048 floats).
//  K2: QK^T once, p = exp(s)*inv, attn write (via LDS layout transform), PV MFMA.
// Both use qt=j paired with qt=15-j inside one block -> uniform 17 tiles/block
// (imbalance fix that does NOT rely on block->CU placement).

#define SLEN 2048
#define EMB  1024
#define DK   64
#define BK   128

typedef __attribute__((ext_vector_type(8))) short short8;   // 8 bf16 = MFMA A/B frag
typedef __attribute__((ext_vector_type(4))) float floatx4;  // MFMA C/D frag
typedef __attribute__((ext_vector_type(4))) short short4v;
typedef __attribute__((ext_vector_type(2))) short short2v;

__device__ __forceinline__ short f2bf(float f) {
    union { float f; unsigned u; } c; c.f = f;
    unsigned u = c.u + 0x7fffu + ((c.u >> 16) & 1u);   // RNE
    return (short)(u >> 16);
}
__device__ __forceinline__ float bf2f(short s) {
    union { unsigned u; float f; } c;
    c.u = ((unsigned)(unsigned short)s) << 16;
    return c.f;
}

#define KS_LD 72    // K tile   [128][64]  bf16, stride 72  (144 B, 16B-aligned)
#define VT_LD 136   // V^T tile [64][128]  bf16, stride 136 (272 B, 16B-aligned)
#define PS_LD 136   // P tile   [64][128]  bf16, stride 136

// Decode: half = g&1, j = (g>>1)&7, bh = g>>4  (16 consecutive blocks share bh
// -> K/V slice of that head stays hot in the XCD L2s they spread across).
__device__ __forceinline__ void decode_block(int g, int& bh, int& j, int& half) {
    half = g & 1;
    j    = (g >> 1) & 7;
    bh   = g >> 4;
}

// Load Q fragments for a 16-row strip starting at grow, scaled by 1/8.
__device__ __forceinline__ void load_q_frags(const float* __restrict__ Q, int b, int h,
                                             int grow, int quad, short8* aq /*[2]*/) {
    const float* qp = Q + (size_t)(b * SLEN + grow) * EMB + h * DK;
#pragma unroll
    for (int ch = 0; ch < 2; ++ch) {
        const float4* p4 = (const float4*)(qp + ch * 32 + quad * 8);
        float4 x0 = p4[0], x1 = p4[1];
        short8 a;
        a[0] = f2bf(x0.x * 0.125f); a[1] = f2bf(x0.y * 0.125f);
        a[2] = f2bf(x0.z * 0.125f); a[3] = f2bf(x0.w * 0.125f);
        a[4] = f2bf(x1.x * 0.125f); a[5] = f2bf(x1.y * 0.125f);
        a[6] = f2bf(x1.z * 0.125f); a[7] = f2bf(x1.w * 0.125f);
        aq[ch] = a;
    }
}

// Stage one 128x64 K tile (rows k0..k0+128 of head h) into Ks as bf16.
__device__ __forceinline__ void stage_k(const float* __restrict__ K, int b, int h,
                                        int k0, int t, short* Ks) {
    const int col = (t & 15) * 4;
    const int rb  = t >> 4;
#pragma unroll
    for (int p = 0; p < 8; ++p) {
        const int row = p * 16 + rb;
        const float4 x = *(const float4*)(K + (size_t)(b * SLEN + k0 + row) * EMB + h * DK + col);
        short4v s;
        s[0] = f2bf(x.x); s[1] = f2bf(x.y); s[2] = f2bf(x.z); s[3] = f2bf(x.w);
        *(short4v*)&Ks[row * KS_LD + col] = s;
    }
}

// ===================== K1: inverse row sums =====================
__global__ __launch_bounds__(256, 4)
void rowsum_kernel(const float* __restrict__ Q, const float* __restrict__ K,
                   float* __restrict__ invbuf)
{
    __shared__ short Ks[BK * KS_LD];   // 18,432 B

    int bh, j, half; decode_block(blockIdx.x, bh, j, half);
    const int b = bh >> 4, h = bh & 15;
    const int qt[2]    = { j, 15 - j };
    const int qbase[2] = { qt[0] * 128 + half * 64, qt[1] * 128 + half * 64 };

    const int t    = threadIdx.x;
    const int w    = t >> 6;
    const int lane = t & 63;
    const int quad = lane >> 4;
    const int l15  = lane & 15;

    short8 aq[2][2];
    load_q_frags(Q, b, h, qbase[0] + w * 16 + l15, quad, aq[0]);
    load_q_frags(Q, b, h, qbase[1] + w * 16 + l15, quad, aq[1]);

    float rs[2][4];
#pragma unroll
    for (int qh = 0; qh < 2; ++qh)
#pragma unroll
        for (int r = 0; r < 4; ++r) rs[qh][r] = 0.f;

    const int ktmax = 15 - j;   // qt[1] needs 0..15-j (superset of qt[0]'s 0..j)
    for (int kt = 0; kt <= ktmax; ++kt) {
        const int k0 = kt * BK;
        __syncthreads();
        stage_k(K, b, h, k0, t, Ks);
        __syncthreads();
#pragma unroll
        for (int n = 0; n < 8; ++n) {
            const short8 b0 = *(const short8*)&Ks[(n * 16 + l15) * KS_LD + quad * 8];
            const short8 b1 = *(const short8*)&Ks[(n * 16 + l15) * KS_LD + 32 + quad * 8];
            const int colg = k0 + n * 16 + l15;
#pragma unroll
            for (int qh = 0; qh < 2; ++qh) {
                if (qh == 0 && kt > j) continue;       // block-uniform
                floatx4 c = {0.f, 0.f, 0.f, 0.f};
                c = __builtin_amdgcn_mfma_f32_16x16x32_bf16(aq[qh][0], b0, c, 0, 0, 0);
                c = __builtin_amdgcn_mfma_f32_16x16x32_bf16(aq[qh][1], b1, c, 0, 0, 0);
                const int rowg = qbase[qh] + w * 16 + quad * 4;
                const bool diag = (kt == qt[qh]);
#pragma unroll
                for (int r = 0; r < 4; ++r) {
                    const float p = (!diag || (colg <= rowg + r)) ? __expf(c[r]) : 0.f;
                    rs[qh][r] += p;
                }
            }
        }
    }

#pragma unroll
    for (int qh = 0; qh < 2; ++qh)
#pragma unroll
        for (int r = 0; r < 4; ++r) {
            float v = rs[qh][r];
            v += __shfl_xor(v, 1);
            v += __shfl_xor(v, 2);
            v += __shfl_xor(v, 4);
            v += __shfl_xor(v, 8);
            if (l15 == 0)
                invbuf[(size_t)bh * SLEN + qbase[qh] + w * 16 + quad * 4 + r] = 1.0f / v;
        }
}

// ===================== K2: attn + out =====================
__global__ __launch_bounds__(256, 3)
void attn_main_kernel(const float* __restrict__ Q, const float* __restrict__ K,
                      const float* __restrict__ V, const float* __restrict__ invbuf,
                      float* __restrict__ out, float* __restrict__ attn)
{
    __shared__ short Ks[BK * KS_LD];   // 18,432 B
    __shared__ short Vt[DK * VT_LD];   // 17,408 B
    __shared__ short Ps[64 * PS_LD];   // 17,408 B   (total 53,248 B -> 3 blocks/CU)

    int bh, j, half; decode_block(blockIdx.x, bh, j, half);
    const int b = bh >> 4, h = bh & 15;
    const int qt[2]    = { j, 15 - j };
    const int qbase[2] = { qt[0] * 128 + half * 64, qt[1] * 128 + half * 64 };

    const int t    = threadIdx.x;
    const int w    = t >> 6;
    const int lane = t & 63;
    const int quad = lane >> 4;
    const int l15  = lane & 15;

    short8 aq[2][2];
    load_q_frags(Q, b, h, qbase[0] + w * 16 + l15, quad, aq[0]);
    load_q_frags(Q, b, h, qbase[1] + w * 16 + l15, quad, aq[1]);

    float invr[2][4];
#pragma unroll
    for (int qh = 0; qh < 2; ++qh)
#pragma unroll
        for (int r = 0; r < 4; ++r)
            invr[qh][r] = invbuf[(size_t)bh * SLEN + qbase[qh] + w * 16 + quad * 4 + r];

    floatx4 o[2][4];
#pragma unroll
    for (int qh = 0; qh < 2; ++qh)
#pragma unroll
        for (int n = 0; n < 4; ++n) o[qh][n] = (floatx4){0.f, 0.f, 0.f, 0.f};

    float* const attn_bh = attn + (size_t)bh * SLEN * SLEN;

    const int ktmax = 15 - j;
    for (int kt = 0; kt <= ktmax; ++kt) {
        const int k0 = kt * BK;
        stage_k(K, b, h, k0, t, Ks);
        // stage V^T: pack (k, k+1) bf16 pairs per d -> 4B LDS writes
        {
            const int kp = t & 63;
            const int dg = t >> 6;
#pragma unroll
            for (int p = 0; p < 4; ++p) {
                const int db = p * 16 + dg * 4;
                const float* vb = V + (size_t)(b * SLEN + k0 + 2 * kp) * EMB + h * DK + db;
                const float4 x0 = *(const float4*)vb;
                const float4 x1 = *(const float4*)(vb + EMB);
                short2v s;
                s[0] = f2bf(x0.x); s[1] = f2bf(x1.x); *(short2v*)&Vt[(db + 0) * VT_LD + 2 * kp] = s;
                s[0] = f2bf(x0.y); s[1] = f2bf(x1.y); *(short2v*)&Vt[(db + 1) * VT_LD + 2 * kp] = s;
                s[0] = f2bf(x0.z); s[1] = f2bf(x1.z); *(short2v*)&Vt[(db + 2) * VT_LD + 2 * kp] = s;
                s[0] = f2bf(x0.w); s[1] = f2bf(x1.w); *(short2v*)&Vt[(db + 3) * VT_LD + 2 * kp] = s;
            }
        }
        __syncthreads();

#pragma unroll
        for (int qh = 0; qh < 2; ++qh) {
            if (qh == 0 && kt > j) continue;   // block-uniform skip
            const bool diag = (kt == qt[qh]);
            // QK^T once, normalize, P -> LDS
#pragma unroll
            for (int n = 0; n < 8; ++n) {
                const short8 b0 = *(const short8*)&Ks[(n * 16 + l15) * KS_LD + quad * 8];
                const short8 b1 = *(const short8*)&Ks[(n * 16 + l15) * KS_LD + 32 + quad * 8];
                const int colg = k0 + n * 16 + l15;
                floatx4 c = {0.f, 0.f, 0.f, 0.f};
                c = __builtin_amdgcn_mfma_f32_16x16x32_bf16(aq[qh][0], b0, c, 0, 0, 0);
                c = __builtin_amdgcn_mfma_f32_16x16x32_bf16(aq[qh][1], b1, c, 0, 0, 0);
                const int rowl = w * 16 + quad * 4;
                const int rowg = qbase[qh] + rowl;
#pragma unroll
                for (int r = 0; r < 4; ++r) {
                    const float p = (!diag || (colg <= rowg + r))
                                        ? __expf(c[r]) * invr[qh][r] : 0.f;
                    Ps[(rowl + r) * PS_LD + n * 16 + l15] = f2bf(p);
                }
            }
            __syncthreads();
            // attn writeback: 64 rows x 512 B, fully coalesced
            {
                const int c4 = (t & 31) * 4;
                const int rb = t >> 5;
#pragma unroll
                for (int i = 0; i < 8; ++i) {
                    const int row = i * 8 + rb;
                    const short4v pv = *(const short4v*)&Ps[row * PS_LD + c4];
                    float4 f;
                    f.x = bf2f(pv[0]); f.y = bf2f(pv[1]); f.z = bf2f(pv[2]); f.w = bf2f(pv[3]);
                    *(float4*)(attn_bh + (size_t)(qbase[qh] + row) * SLEN + k0 + c4) = f;
                }
            }
            // PV: o += P * V
#pragma unroll
            for (int ch = 0; ch < 4; ++ch) {
                const short8 ap = *(const short8*)&Ps[(w * 16 + l15) * PS_LD + ch * 32 + quad * 8];
#pragma unroll
                for (int n = 0; n < 4; ++n) {
                    const short8 bv = *(const short8*)&Vt[(n * 16 + l15) * VT_LD + ch * 32 + quad * 8];
                    o[qh][n] = __builtin_amdgcn_mfma_f32_16x16x32_bf16(ap, bv, o[qh][n], 0, 0, 0);
                }
            }
            __syncthreads();
        }
    }

    // ---- out tiles ----
#pragma unroll
    for (int qh = 0; qh < 2; ++qh) {
        const int rowg = qbase[qh] + w * 16 + quad * 4;
#pragma unroll
        for (int n = 0; n < 4; ++n) {
            const int col = h * DK + n * 16 + l15;
#pragma unroll
            for (int r = 0; r < 4; ++r)
                out[(size_t)(b * SLEN + rowg + r) * EMB + col] = o[qh][n][r];
        }
    }

    // ---- zero-fill masked attn region (uniform 15 tiles/block total) ----
    const float4 z = {0.f, 0.f, 0.f, 0.f};
#pragma unroll
    for (int qh = 0; qh < 2; ++qh) {
        const int z0 = (qt[qh] + 1) * BK;
        if (z0 >= SLEN) continue;
        for (int row = w; row < 64; row += 4) {
            float* rp = attn_bh + (size_t)(qbase[qh] + row) * SLEN;
            for (int c = z0 + lane * 4; c < SLEN; c += 256)
                *(float4*)(rp + c) = z;
        }
    }
}

extern "C" void kernel_launch(void* const* d_in, const int* in_sizes, int n_in,
                              void* d_out, int out_size, void* d_ws, size_t ws_size,
                              hipStream_t stream) {
    const float* Q = (const float*)d_in[0];
    const float* K = (const float*)d_in[1];
    const float* V = (const float*)d_in[2];
    float* out    = (float*)d_out;
    float* attn   = out + (size_t)2 * SLEN * EMB;
    float* invbuf = (float*)d_ws;                  // 2*16*2048 floats = 256 KB

    rowsum_kernel<<<dim3(512), dim3(256), 0, stream>>>(Q, K, invbuf);
    attn_main_kernel<<<dim3(512), dim3(256), 0, stream>>>(Q, K, V, invbuf, out, attn);
}

// Round 3
// 652.509 us; speedup vs baseline: 1.1323x; 1.1323x over previous
//
#include <hip/hip_runtime.h>
#include <cstdint>
#include <cstddef>

// Multi-head causal attention forward. B=2, H=16, S=2048, EMBED=1024, D_K=64.
// d_out = out [2,2048,1024] fp32 ++ attn [2,16,2048,2048] fp32  (553.6 MB).
//
// Single fused kernel, balanced: block = (bh, j, half64) handles q-tiles j and
// 15-j (64-row strips) -> uniform 17 score-tiles + 15 zero-tiles per block.
// Pass A: rowsums of exp (inv kept in registers). Pass B: QK^T, normalize,
// attn write via LDS transform, PV MFMA. K/V staged with register-level
// prefetch (next tile's global loads issued under current tile's compute).
// Zero-fill of the masked upper triangle interleaved into the pass-B loop.

#define SLEN 2048
#define EMB  1024
#define DK   64
#define BK   128

typedef __attribute__((ext_vector_type(8))) short short8;   // 8 bf16 = MFMA A/B frag
typedef __attribute__((ext_vector_type(4))) float floatx4;  // MFMA C/D frag
typedef __attribute__((ext_vector_type(4))) short short4v;
typedef __attribute__((ext_vector_type(2))) short short2v;

__device__ __forceinline__ short f2bf(float f) {
    union { float f; unsigned u; } c; c.f = f;
    unsigned u = c.u + 0x7fffu + ((c.u >> 16) & 1u);   // RNE
    return (short)(u >> 16);
}
__device__ __forceinline__ float bf2f(short s) {
    union { unsigned u; float f; } c;
    c.u = ((unsigned)(unsigned short)s) << 16;
    return c.f;
}

#define KS_LD 72    // K tile   [128][64]  bf16, stride 72  (144 B, 16B-aligned)
#define VT_LD 136   // V^T tile [64][128]  bf16, stride 136 (272 B, 16B-aligned)
#define PS_LD 136   // P tile   [64][128]  bf16, stride 136

__global__ __launch_bounds__(256, 2)
void attn_fused_kernel(const float* __restrict__ Q, const float* __restrict__ K,
                       const float* __restrict__ V, float* __restrict__ out,
                       float* __restrict__ attn)
{
    __shared__ short Ks[BK * KS_LD];   // 18,432 B
    __shared__ short Vt[DK * VT_LD];   // 17,408 B
    __shared__ short Ps[64 * PS_LD];   // 17,408 B  (53,248 B total)

    const int g    = blockIdx.x;
    const int half = g & 1;
    const int j    = (g >> 1) & 7;
    const int bh   = g >> 4;
    const int b    = bh >> 4, h = bh & 15;
    const int qt[2]    = { j, 15 - j };
    const int qbase[2] = { qt[0] * 128 + half * 64, qt[1] * 128 + half * 64 };

    const int t    = threadIdx.x;
    const int w    = t >> 6;
    const int lane = t & 63;
    const int quad = lane >> 4;
    const int l15  = lane & 15;

    // staging index precompute
    const int kcol = (t & 15) * 4;          // K stage: col within 64
    const int krb  = t >> 4;                //          row base (16 rows/pass)
    const int vkp  = t & 63;                // V stage: k-pair index
    const int vdg  = t >> 6;                //          d group

    // ---- Q fragments (scaled by 1/8), held for the whole kernel ----
    short8 aq[2][2];
#pragma unroll
    for (int qh = 0; qh < 2; ++qh) {
        const float* qp = Q + (size_t)(b * SLEN + qbase[qh] + w * 16 + l15) * EMB + h * DK;
#pragma unroll
        for (int ch = 0; ch < 2; ++ch) {
            const float4* p4 = (const float4*)(qp + ch * 32 + quad * 8);
            float4 x0 = p4[0], x1 = p4[1];
            short8 a;
            a[0] = f2bf(x0.x * 0.125f); a[1] = f2bf(x0.y * 0.125f);
            a[2] = f2bf(x0.z * 0.125f); a[3] = f2bf(x0.w * 0.125f);
            a[4] = f2bf(x1.x * 0.125f); a[5] = f2bf(x1.y * 0.125f);
            a[6] = f2bf(x1.z * 0.125f); a[7] = f2bf(x1.w * 0.125f);
            aq[qh][ch] = a;
        }
    }

    const int ktmax = 15 - j;   // qt[1] needs kt 0..15-j (superset of qt[0]'s 0..j)

    // ================= Pass A: inverse row sums =================
    float rs[2][4];
#pragma unroll
    for (int qh = 0; qh < 2; ++qh)
#pragma unroll
        for (int r = 0; r < 4; ++r) rs[qh][r] = 0.f;

    float4 kpre[8];
#pragma unroll
    for (int p = 0; p < 8; ++p)
        kpre[p] = *(const float4*)(K + (size_t)(b * SLEN + p * 16 + krb) * EMB + h * DK + kcol);

    for (int kt = 0; kt <= ktmax; ++kt) {
        // commit prefetched K tile to LDS
#pragma unroll
        for (int p = 0; p < 8; ++p) {
            short4v s;
            s[0] = f2bf(kpre[p].x); s[1] = f2bf(kpre[p].y);
            s[2] = f2bf(kpre[p].z); s[3] = f2bf(kpre[p].w);
            *(short4v*)&Ks[(p * 16 + krb) * KS_LD + kcol] = s;
        }
        __syncthreads();
        // prefetch next tile (loads overlap the compute below)
        if (kt < ktmax) {
            const int k0n = (kt + 1) * BK;
#pragma unroll
            for (int p = 0; p < 8; ++p)
                kpre[p] = *(const float4*)(K + (size_t)(b * SLEN + k0n + p * 16 + krb) * EMB + h * DK + kcol);
        }
        const int k0 = kt * BK;
#pragma unroll
        for (int n = 0; n < 8; ++n) {
            const short8 b0 = *(const short8*)&Ks[(n * 16 + l15) * KS_LD + quad * 8];
            const short8 b1 = *(const short8*)&Ks[(n * 16 + l15) * KS_LD + 32 + quad * 8];
            const int colg = k0 + n * 16 + l15;
#pragma unroll
            for (int qh = 0; qh < 2; ++qh) {
                if (qh == 0 && kt > j) continue;       // block-uniform skip
                floatx4 c = {0.f, 0.f, 0.f, 0.f};
                c = __builtin_amdgcn_mfma_f32_16x16x32_bf16(aq[qh][0], b0, c, 0, 0, 0);
                c = __builtin_amdgcn_mfma_f32_16x16x32_bf16(aq[qh][1], b1, c, 0, 0, 0);
                const int rowg = qbase[qh] + w * 16 + quad * 4;
                const bool diag = (kt == qt[qh]);
#pragma unroll
                for (int r = 0; r < 4; ++r) {
                    const float p = (!diag || (colg <= rowg + r)) ? __expf(c[r]) : 0.f;
                    rs[qh][r] += p;
                }
            }
        }
        __syncthreads();
    }

    float invr[2][4];
#pragma unroll
    for (int qh = 0; qh < 2; ++qh)
#pragma unroll
        for (int r = 0; r < 4; ++r) {
            float v = rs[qh][r];
            v += __shfl_xor(v, 1);
            v += __shfl_xor(v, 2);
            v += __shfl_xor(v, 4);
            v += __shfl_xor(v, 8);
            invr[qh][r] = 1.0f / v;
        }

    // ================= Pass B: attn + out =================
    floatx4 o[2][4];
#pragma unroll
    for (int qh = 0; qh < 2; ++qh)
#pragma unroll
        for (int n = 0; n < 4; ++n) o[qh][n] = (floatx4){0.f, 0.f, 0.f, 0.f};

    float* const attn_bh = attn + (size_t)bh * SLEN * SLEN;

    float4 vpre[8];
#pragma unroll
    for (int p = 0; p < 8; ++p)
        kpre[p] = *(const float4*)(K + (size_t)(b * SLEN + p * 16 + krb) * EMB + h * DK + kcol);
#pragma unroll
    for (int p = 0; p < 4; ++p) {
        const float* vb = V + (size_t)(b * SLEN + 2 * vkp) * EMB + h * DK + p * 16 + vdg * 4;
        vpre[2 * p]     = *(const float4*)vb;
        vpre[2 * p + 1] = *(const float4*)(vb + EMB);
    }

    for (int kt = 0; kt <= ktmax; ++kt) {
        // commit prefetched K and V^T tiles to LDS
#pragma unroll
        for (int p = 0; p < 8; ++p) {
            short4v s;
            s[0] = f2bf(kpre[p].x); s[1] = f2bf(kpre[p].y);
            s[2] = f2bf(kpre[p].z); s[3] = f2bf(kpre[p].w);
            *(short4v*)&Ks[(p * 16 + krb) * KS_LD + kcol] = s;
        }
#pragma unroll
        for (int p = 0; p < 4; ++p) {
            const int db = p * 16 + vdg * 4;
            const float4 x0 = vpre[2 * p], x1 = vpre[2 * p + 1];
            short2v s;
            s[0] = f2bf(x0.x); s[1] = f2bf(x1.x); *(short2v*)&Vt[(db + 0) * VT_LD + 2 * vkp] = s;
            s[0] = f2bf(x0.y); s[1] = f2bf(x1.y); *(short2v*)&Vt[(db + 1) * VT_LD + 2 * vkp] = s;
            s[0] = f2bf(x0.z); s[1] = f2bf(x1.z); *(short2v*)&Vt[(db + 2) * VT_LD + 2 * vkp] = s;
            s[0] = f2bf(x0.w); s[1] = f2bf(x1.w); *(short2v*)&Vt[(db + 3) * VT_LD + 2 * vkp] = s;
        }
        __syncthreads();
        // prefetch next K/V tile under this tile's compute
        if (kt < ktmax) {
            const int k0n = (kt + 1) * BK;
#pragma unroll
            for (int p = 0; p < 8; ++p)
                kpre[p] = *(const float4*)(K + (size_t)(b * SLEN + k0n + p * 16 + krb) * EMB + h * DK + kcol);
#pragma unroll
            for (int p = 0; p < 4; ++p) {
                const float* vb = V + (size_t)(b * SLEN + k0n + 2 * vkp) * EMB + h * DK + p * 16 + vdg * 4;
                vpre[2 * p]     = *(const float4*)vb;
                vpre[2 * p + 1] = *(const float4*)(vb + EMB);
            }
        }
        const int k0 = kt * BK;

#pragma unroll
        for (int qh = 0; qh < 2; ++qh) {
            if (qh == 0 && kt > j) continue;   // block-uniform skip
            const bool diag = (kt == qt[qh]);
            // QK^T, normalize, P -> LDS
#pragma unroll
            for (int n = 0; n < 8; ++n) {
                const short8 b0 = *(const short8*)&Ks[(n * 16 + l15) * KS_LD + quad * 8];
                const short8 b1 = *(const short8*)&Ks[(n * 16 + l15) * KS_LD + 32 + quad * 8];
                const int colg = k0 + n * 16 + l15;
                floatx4 c = {0.f, 0.f, 0.f, 0.f};
                c = __builtin_amdgcn_mfma_f32_16x16x32_bf16(aq[qh][0], b0, c, 0, 0, 0);
                c = __builtin_amdgcn_mfma_f32_16x16x32_bf16(aq[qh][1], b1, c, 0, 0, 0);
                const int rowl = w * 16 + quad * 4;
                const int rowg = qbase[qh] + rowl;
#pragma unroll
                for (int r = 0; r < 4; ++r) {
                    const float p = (!diag || (colg <= rowg + r))
                                        ? __expf(c[r]) * invr[qh][r] : 0.f;
                    Ps[(rowl + r) * PS_LD + n * 16 + l15] = f2bf(p);
                }
            }
            __syncthreads();
            // attn writeback: 64 rows x 512 B, fully coalesced
            {
                const int c4 = (t & 31) * 4;
                const int rb = t >> 5;
#pragma unroll
                for (int i = 0; i < 8; ++i) {
                    const int row = i * 8 + rb;
                    const short4v pv = *(const short4v*)&Ps[row * PS_LD + c4];
                    float4 f;
                    f.x = bf2f(pv[0]); f.y = bf2f(pv[1]); f.z = bf2f(pv[2]); f.w = bf2f(pv[3]);
                    *(float4*)(attn_bh + (size_t)(qbase[qh] + row) * SLEN + k0 + c4) = f;
                }
            }
            // PV: o += P * V
#pragma unroll
            for (int ch = 0; ch < 4; ++ch) {
                const short8 ap = *(const short8*)&Ps[(w * 16 + l15) * PS_LD + ch * 32 + quad * 8];
#pragma unroll
                for (int n = 0; n < 4; ++n) {
                    const short8 bv = *(const short8*)&Vt[(n * 16 + l15) * VT_LD + ch * 32 + quad * 8];
                    o[qh][n] = __builtin_amdgcn_mfma_f32_16x16x32_bf16(ap, bv, o[qh][n], 0, 0, 0);
                }
            }
            __syncthreads();
        }

        // interleaved zero-fill of masked tiles (uniform 15/block total):
        //   kt in (j, 15-j]  -> zero (qh0, kt)
        //   kt in [1, j]     -> zero (qh0, 15-j+kt) and (qh1, 15-j+kt)
        {
            const int c4 = (t & 31) * 4;
            const int rb = t >> 5;
            const float4 z = {0.f, 0.f, 0.f, 0.f};
            if (kt > j) {
                float* base = attn_bh + (size_t)qbase[0] * SLEN + kt * BK;
#pragma unroll
                for (int i = 0; i < 8; ++i)
                    *(float4*)(base + (size_t)(i * 8 + rb) * SLEN + c4) = z;
            }
            if (kt >= 1 && kt <= j) {
                const int zt = 15 - j + kt;
                float* base0 = attn_bh + (size_t)qbase[0] * SLEN + zt * BK;
                float* base1 = attn_bh + (size_t)qbase[1] * SLEN + zt * BK;
#pragma unroll
                for (int i = 0; i < 8; ++i) {
                    *(float4*)(base0 + (size_t)(i * 8 + rb) * SLEN + c4) = z;
                    *(float4*)(base1 + (size_t)(i * 8 + rb) * SLEN + c4) = z;
                }
            }
        }
    }

    // ---- out tiles ----
#pragma unroll
    for (int qh = 0; qh < 2; ++qh) {
        const int rowg = qbase[qh] + w * 16 + quad * 4;
#pragma unroll
        for (int n = 0; n < 4; ++n) {
            const int col = h * DK + n * 16 + l15;
#pragma unroll
            for (int r = 0; r < 4; ++r)
                out[(size_t)(b * SLEN + rowg + r) * EMB + col] = o[qh][n][r];
        }
    }
}

extern "C" void kernel_launch(void* const* d_in, const int* in_sizes, int n_in,
                              void* d_out, int out_size, void* d_ws, size_t ws_size,
                              hipStream_t stream) {
    const float* Q = (const float*)d_in[0];
    const float* K = (const float*)d_in[1];
    const float* V = (const float*)d_in[2];
    float* out  = (float*)d_out;
    float* attn = out + (size_t)2 * SLEN * EMB;
    attn_fused_kernel<<<dim3(512), dim3(256), 0, stream>>>(Q, K, V, out, attn);
}